// Round 9
// baseline (830.156 us; speedup 1.0000x reference)
//
#include <hip/hip_runtime.h>
#include <hip/hip_bf16.h>

#define NF 22     // node features
#define H  32     // hidden dim
#define BSH 8     // 256 nodes per bucket
#define CAP 8192  // edge capacity per bucket (mean 4096 at E=1.6M, NB=391)
#define BCHUNK 4096
// requires N <= 131072 (src fits 24 bits after <<8 shift; bucket count <= 512)

__device__ __forceinline__ float bflo(unsigned int v) { return __uint_as_float(v << 16); }
__device__ __forceinline__ float bfhi(unsigned int v) { return __uint_as_float(v & 0xffff0000u); }
__device__ __forceinline__ unsigned int packbf2(float a, float b) {
    __hip_bfloat162 p; p.x = __float2bfloat16(a); p.y = __float2bfloat16(b);
    return *(unsigned int*)&p;
}

// unpack 8 bf16 (uint4) into 8 consecutive floats  (param name must not be 'x'/'y'/'z'/'w':
// macro substitution would also rewrite the member-access tokens)
#define UNPK8(ar, off, vv) { (ar)[(off)+0]=bflo((vv).x); (ar)[(off)+1]=bfhi((vv).x); \
    (ar)[(off)+2]=bflo((vv).y); (ar)[(off)+3]=bfhi((vv).y); \
    (ar)[(off)+4]=bflo((vv).z); (ar)[(off)+5]=bfhi((vv).z); \
    (ar)[(off)+6]=bflo((vv).w); (ar)[(off)+7]=bfhi((vv).w); }

// ---- bin edges by dst bucket via per-chunk LDS counting sort; coalesced writes ----
__global__ __launch_bounds__(512) void bin_edges(
    const int* __restrict__ src, const int* __restrict__ dst,
    int* __restrict__ cursor, int* __restrict__ binned, int E, int NB)
{
    __shared__ int vals[BCHUNK];
    __shared__ unsigned short bkts[BCHUNK];
    __shared__ int svals[BCHUNK];
    __shared__ unsigned short sbkt[BCHUNK];
    __shared__ int scnt[512];
    __shared__ int sex[512];
    __shared__ int lcur[512];
    __shared__ int gbase[512];
    __shared__ int wsum[8];

    int tid = threadIdx.x;
    scnt[tid] = 0;
    __syncthreads();

    int e0 = blockIdx.x * BCHUNK;
    int n = min(e0 + BCHUNK, E) - e0;

    for (int i = tid; i < n; i += 512) {
        int d = dst[e0 + i];
        int b = d >> BSH;
        vals[i] = (src[e0 + i] << BSH) | (d & 255);
        bkts[i] = (unsigned short)b;
        atomicAdd(&scnt[b], 1);
    }
    __syncthreads();

    int c = scnt[tid];
    int lane = tid & 63, w = tid >> 6;
    int v = c;
#pragma unroll
    for (int off = 1; off < 64; off <<= 1) {
        int t = __shfl_up(v, off, 64);
        if (lane >= off) v += t;
    }
    if (lane == 63) wsum[w] = v;
    __syncthreads();
    int wbase = 0;
    for (int k = 0; k < w; k++) wbase += wsum[k];
    int ex = v + wbase - c;
    sex[tid] = ex;
    lcur[tid] = ex;
    if (c) gbase[tid] = tid * CAP + atomicAdd(&cursor[tid], c);
    __syncthreads();

    for (int i = tid; i < n; i += 512) {
        int b = bkts[i];
        int p = atomicAdd(&lcur[b], 1);
        svals[p] = vals[i];
        sbkt[p] = (unsigned short)b;
    }
    __syncthreads();

    for (int i = tid; i < n; i += 512) {
        int b = sbkt[i];
        binned[gbase[b] + (i - sex[b])] = svals[i];
    }
}

// ---- per-bucket degree count -> dis (rsqrt(deg+1)) ----
__global__ __launch_bounds__(256) void bucket_deg(
    const int* __restrict__ cursor, const int* __restrict__ binned,
    float* __restrict__ dis, int N)
{
    __shared__ int cnt[256];
    int b = blockIdx.x, tid = threadIdx.x;
    cnt[tid] = 0;
    __syncthreads();
    int es = b * CAP, ee = es + min(cursor[b], CAP);
    for (int i = es + tid; i < ee; i += 256) atomicAdd(&cnt[binned[i] & 255], 1);
    __syncthreads();
    int nn = (b << BSH) + tid;
    if (nn < N) dis[nn] = rsqrtf((float)(cnt[tid] + 1));
}

// ---- embed + ALL node-local products ----
__global__ __launch_bounds__(256) void embed_g1(
    const float* __restrict__ x, const float* __restrict__ We,
    const float* __restrict__ be, const float* __restrict__ W1,
    const float* __restrict__ W2, const float* __restrict__ Wp,
    const float* __restrict__ bp, const float* __restrict__ dis,
    __hip_bfloat16* __restrict__ g, __hip_bfloat16* __restrict__ y2,
    float* __restrict__ hp, int N)
{
    __shared__ float sWe[NF * H];
    __shared__ float sW1[H * H];
    __shared__ float sW2b[H * H];
    __shared__ float sbe[H];
    __shared__ float sWpb[H];
    __shared__ float sx[8][NF];
    __shared__ float sh[8][H];

    int tid = threadIdx.x;
    for (int j = tid; j < NF * H; j += 256) sWe[j] = We[j];
    for (int j = tid; j < H * H; j += 256) sW1[j] = W1[j];
    for (int j = tid; j < H * H; j += 256) sW2b[j] = W2[H * H + j];
    if (tid < H) sbe[tid] = be[tid];
    if (tid >= H && tid < 2 * H) sWpb[tid - H] = Wp[tid];

    int grp = tid >> 5, t = tid & 31;
    int ngrp = (N + 7) >> 3;
    for (int nb = blockIdx.x; nb < ngrp; nb += gridDim.x) {
        int node = nb * 8 + grp;
        int nodec = node < N ? node : N - 1;
        __syncthreads();
        if (t < NF) sx[grp][t] = x[(size_t)nodec * NF + t];
        __syncthreads();

        float h = sbe[t];
#pragma unroll
        for (int k = 0; k < NF; k++) h += sx[grp][k] * sWe[k * H + t];
        sh[grp][t] = h;
        __syncthreads();

        float di = dis[nodec];
        float gv = 0.f, yv = 0.f;
#pragma unroll
        for (int k = 0; k < H; k++) {
            float hv = sh[grp][k];
            gv += hv * sW1[k * H + t];
            yv += hv * sW2b[k * H + t];
        }
        gv *= di;

        float pv = h * sWpb[t];
#pragma unroll
        for (int off = 16; off > 0; off >>= 1) pv += __shfl_down(pv, off, 32);

        if (node < N) {
            size_t o = (size_t)node * H + t;
            g[o] = __float2bfloat16(gv);
            y2[o] = __float2bfloat16(yv);
            if (t == 0) hp[node] = pv + bp[0] + sx[grp][1];
        }
    }
}

// 4 LDS float atomic-adds for one lane's 4 channels of one edge
#define ATOM4(dl, vv) { float* r_ = &acc[(dl)][l8 * 4]; \
    atomicAdd(r_ + 0, bflo((vv).x)); atomicAdd(r_ + 1, bfhi((vv).x)); \
    atomicAdd(r_ + 2, bflo((vv).y)); atomicAdd(r_ + 3, bfhi((vv).y)); }

// ---- edge-centric gather #1 + mid layer, bucket-resident LDS accumulator ----
// No adjacency materialization, no per-node walk, no degree divergence: a block
// streams its bucket's binned edges (sequential), gathers random 64B g1 rows,
// accumulates in LDS (33-pad -> conflict-light), then does the mid-layer in-block.
__global__ __launch_bounds__(512) void bucket_agg_mid(
    const int* __restrict__ cursor, const int* __restrict__ binned,
    const float* __restrict__ dis,
    const __hip_bfloat16* __restrict__ g_in, const __hip_bfloat16* __restrict__ y2,
    const float* __restrict__ W2, const float* __restrict__ b1,
    __hip_bfloat16* __restrict__ g_out, int N)
{
    __shared__ float acc[256][33];   // 33.8 KB, pad kills bank conflicts
    __shared__ float sW2[H * H];     // W2 rows 0..31 (4 KB)
    int tid = threadIdx.x;
    int b = blockIdx.x, bn = b << BSH;
    for (int j = tid; j < H * H; j += 512) sW2[j] = W2[j];

    // init acc with self g1 rows (self-loop term): thread = (node, half16)
    int nd = tid >> 1, hf = tid & 1;
    int nodec = min(bn + nd, N - 1);
    const uint4* g4 = (const uint4*)g_in;
    {
        uint4 va = g4[(size_t)nodec * 4 + hf * 2];
        uint4 vb = g4[(size_t)nodec * 4 + hf * 2 + 1];
        float* ar = &acc[nd][hf * 16];
        UNPK8(ar, 0, va) UNPK8(ar, 8, vb)
    }
    __syncthreads();

    // stream edges: 64 groups x 8 lanes; unroll 4 for memory-level parallelism
    const uint2* g2v = (const uint2*)g_in;
    int grp = tid >> 3, l8 = tid & 7;
    int es = b * CAP, ee = es + min(cursor[b], CAP);
    int e = es + grp;
    for (; e + 192 < ee; e += 256) {
        int v0 = binned[e], v1 = binned[e + 64], v2 = binned[e + 128], v3 = binned[e + 192];
        uint2 x0 = g2v[(size_t)(v0 >> BSH) * 8 + l8];
        uint2 x1 = g2v[(size_t)(v1 >> BSH) * 8 + l8];
        uint2 x2 = g2v[(size_t)(v2 >> BSH) * 8 + l8];
        uint2 x3 = g2v[(size_t)(v3 >> BSH) * 8 + l8];
        ATOM4(v0 & 255, x0) ATOM4(v1 & 255, x1) ATOM4(v2 & 255, x2) ATOM4(v3 & 255, x3)
    }
    for (; e < ee; e += 64) {
        int v = binned[e];
        uint2 xv = g2v[(size_t)(v >> BSH) * 8 + l8];
        ATOM4(v & 255, xv)
    }
    __syncthreads();

    // epilogue pass 1: srow = relu(di*acc + b1), in place
    float di = dis[nodec];
    {
        float* ar = &acc[nd][hf * 16];
        const float4* b1v = (const float4*)b1;
        float4 ba = b1v[hf * 4], bbv = b1v[hf * 4 + 1];
        float4 bc = b1v[hf * 4 + 2], bd = b1v[hf * 4 + 3];
        ar[0] = fmaxf(di * ar[0] + ba.x, 0.f);  ar[1] = fmaxf(di * ar[1] + ba.y, 0.f);
        ar[2] = fmaxf(di * ar[2] + ba.z, 0.f);  ar[3] = fmaxf(di * ar[3] + ba.w, 0.f);
        ar[4] = fmaxf(di * ar[4] + bbv.x, 0.f); ar[5] = fmaxf(di * ar[5] + bbv.y, 0.f);
        ar[6] = fmaxf(di * ar[6] + bbv.z, 0.f); ar[7] = fmaxf(di * ar[7] + bbv.w, 0.f);
        ar[8] = fmaxf(di * ar[8] + bc.x, 0.f);  ar[9] = fmaxf(di * ar[9] + bc.y, 0.f);
        ar[10] = fmaxf(di * ar[10] + bc.z, 0.f); ar[11] = fmaxf(di * ar[11] + bc.w, 0.f);
        ar[12] = fmaxf(di * ar[12] + bd.x, 0.f); ar[13] = fmaxf(di * ar[13] + bd.y, 0.f);
        ar[14] = fmaxf(di * ar[14] + bd.z, 0.f); ar[15] = fmaxf(di * ar[15] + bd.w, 0.f);
    }
    __syncthreads();

    // epilogue pass 2: o = srow . W2[0:32, hf*16:+16] (+ y2), scale, pack
    float o[16];
#pragma unroll
    for (int c = 0; c < 16; c++) o[c] = 0.f;
    const float4* sW2v = (const float4*)sW2;
#pragma unroll
    for (int k = 0; k < H; k++) {
        float rv = acc[nd][k];
        float4 w0 = sW2v[k * 8 + hf * 4];
        float4 w1 = sW2v[k * 8 + hf * 4 + 1];
        float4 w2 = sW2v[k * 8 + hf * 4 + 2];
        float4 w3 = sW2v[k * 8 + hf * 4 + 3];
        o[0] += rv * w0.x;  o[1] += rv * w0.y;  o[2] += rv * w0.z;  o[3] += rv * w0.w;
        o[4] += rv * w1.x;  o[5] += rv * w1.y;  o[6] += rv * w1.z;  o[7] += rv * w1.w;
        o[8] += rv * w2.x;  o[9] += rv * w2.y;  o[10] += rv * w2.z; o[11] += rv * w2.w;
        o[12] += rv * w3.x; o[13] += rv * w3.y; o[14] += rv * w3.z; o[15] += rv * w3.w;
    }
    const uint4* y4 = (const uint4*)y2;
    uint4 ya = y4[(size_t)nodec * 4 + hf * 2];
    uint4 yb = y4[(size_t)nodec * 4 + hf * 2 + 1];
    o[0] = di * (o[0] + bflo(ya.x));  o[1] = di * (o[1] + bfhi(ya.x));
    o[2] = di * (o[2] + bflo(ya.y));  o[3] = di * (o[3] + bfhi(ya.y));
    o[4] = di * (o[4] + bflo(ya.z));  o[5] = di * (o[5] + bfhi(ya.z));
    o[6] = di * (o[6] + bflo(ya.w));  o[7] = di * (o[7] + bfhi(ya.w));
    o[8] = di * (o[8] + bflo(yb.x));  o[9] = di * (o[9] + bfhi(yb.x));
    o[10] = di * (o[10] + bflo(yb.y)); o[11] = di * (o[11] + bfhi(yb.y));
    o[12] = di * (o[12] + bflo(yb.z)); o[13] = di * (o[13] + bfhi(yb.z));
    o[14] = di * (o[14] + bflo(yb.w)); o[15] = di * (o[15] + bfhi(yb.w));

    if (bn + nd < N) {
        uint4 pa, pb;
        pa.x = packbf2(o[0], o[1]);   pa.y = packbf2(o[2], o[3]);
        pa.z = packbf2(o[4], o[5]);   pa.w = packbf2(o[6], o[7]);
        pb.x = packbf2(o[8], o[9]);   pb.y = packbf2(o[10], o[11]);
        pb.z = packbf2(o[12], o[13]); pb.w = packbf2(o[14], o[15]);
        ((uint4*)g_out)[(size_t)(bn + nd) * 4 + hf * 2] = pa;
        ((uint4*)g_out)[(size_t)(bn + nd) * 4 + hf * 2 + 1] = pb;
    }
}

// ---- edge-centric gather #2 + prediction head, bucket-resident ----
__global__ __launch_bounds__(512) void bucket_agg_final(
    const int* __restrict__ cursor, const int* __restrict__ binned,
    const float* __restrict__ dis,
    const __hip_bfloat16* __restrict__ g_in, const float* __restrict__ hp,
    const float* __restrict__ b2, const float* __restrict__ Wp,
    float* __restrict__ out, int N)
{
    __shared__ float acc[256][33];
    __shared__ float sb2[H];
    __shared__ float sWp[H];
    int tid = threadIdx.x;
    int b = blockIdx.x, bn = b << BSH;
    if (tid < H) { sb2[tid] = b2[tid]; sWp[tid] = Wp[tid]; }

    int nd = tid >> 1, hf = tid & 1;
    int nodec = min(bn + nd, N - 1);
    const uint4* g4 = (const uint4*)g_in;
    {
        uint4 va = g4[(size_t)nodec * 4 + hf * 2];
        uint4 vb = g4[(size_t)nodec * 4 + hf * 2 + 1];
        float* ar = &acc[nd][hf * 16];
        UNPK8(ar, 0, va) UNPK8(ar, 8, vb)
    }
    __syncthreads();

    const uint2* g2v = (const uint2*)g_in;
    int grp = tid >> 3, l8 = tid & 7;
    int es = b * CAP, ee = es + min(cursor[b], CAP);
    int e = es + grp;
    for (; e + 192 < ee; e += 256) {
        int v0 = binned[e], v1 = binned[e + 64], v2 = binned[e + 128], v3 = binned[e + 192];
        uint2 x0 = g2v[(size_t)(v0 >> BSH) * 8 + l8];
        uint2 x1 = g2v[(size_t)(v1 >> BSH) * 8 + l8];
        uint2 x2 = g2v[(size_t)(v2 >> BSH) * 8 + l8];
        uint2 x3 = g2v[(size_t)(v3 >> BSH) * 8 + l8];
        ATOM4(v0 & 255, x0) ATOM4(v1 & 255, x1) ATOM4(v2 & 255, x2) ATOM4(v3 & 255, x3)
    }
    for (; e < ee; e += 64) {
        int v = binned[e];
        uint2 xv = g2v[(size_t)(v >> BSH) * 8 + l8];
        ATOM4(v & 255, xv)
    }
    __syncthreads();

    // epilogue: one thread per node
    if (tid < 256) {
        int node = bn + tid;
        float di = dis[min(node, N - 1)];
        float v = 0.f;
#pragma unroll
        for (int k = 0; k < H; k++)
            v += fmaxf(di * acc[tid][k] + sb2[k], 0.f) * sWp[k];
        if (node < N) out[node] = fmaxf(v + hp[node], 0.f);
    }
}

extern "C" void kernel_launch(void* const* d_in, const int* in_sizes, int n_in,
                              void* d_out, int out_size, void* d_ws, size_t ws_size,
                              hipStream_t stream) {
    const float* x  = (const float*)d_in[0];
    const int*   ei = (const int*)d_in[1];
    const float* We = (const float*)d_in[2];
    const float* be = (const float*)d_in[3];
    const float* W1 = (const float*)d_in[4];
    const float* b1 = (const float*)d_in[5];
    const float* W2 = (const float*)d_in[6];
    const float* b2 = (const float*)d_in[7];
    const float* Wp = (const float*)d_in[8];
    const float* bp = (const float*)d_in[9];
    float* out = (float*)d_out;

    const int N = in_sizes[0] / NF;
    const int E = in_sizes[1] / 2;
    const int* src = ei;
    const int* dst = ei + E;
    const int NB = (N + 255) >> BSH;                // 391
    const int nchunk = (E + BCHUNK - 1) / BCHUNK;   // 391

    size_t Np  = ((size_t)N + 127) & ~(size_t)127;
    size_t NHp = ((size_t)N * H + 127) & ~(size_t)127;
    float* ws  = (float*)d_ws;
    float* hp  = ws;                                   // Np
    __hip_bfloat16* g1 = (__hip_bfloat16*)(hp + Np);   // NHp bf16
    __hip_bfloat16* g2 = g1 + NHp;                     // NHp bf16
    __hip_bfloat16* y2 = g2 + NHp;                     // NHp bf16
    int* cursor = (int*)(y2 + NHp);                    // 512
    float* dis  = (float*)(cursor + 512);              // Np
    int* binned = (int*)(dis + Np);                    // NB*CAP

    (void)hipMemsetAsync(cursor, 0, 512 * sizeof(int), stream);
    bin_edges<<<nchunk, 512, 0, stream>>>(src, dst, cursor, binned, E, NB);
    bucket_deg<<<NB, 256, 0, stream>>>(cursor, binned, dis, N);

    int ngrp = (N + 7) >> 3;
    int eg = ngrp < 1536 ? ngrp : 1536;
    embed_g1<<<eg, 256, 0, stream>>>(x, We, be, W1, W2, Wp, bp, dis, g1, y2, hp, N);
    bucket_agg_mid<<<NB, 512, 0, stream>>>(cursor, binned, dis, g1, y2, W2, b1, g2, N);
    bucket_agg_final<<<NB, 512, 0, stream>>>(cursor, binned, dis, g2, hp, b2, Wp, out, N);
}

// Round 10
// 217.633 us; speedup vs baseline: 3.8145x; 3.8145x over previous
//
#include <hip/hip_runtime.h>
#include <hip/hip_bf16.h>

#define NF 22     // node features
#define H  32     // hidden dim
#define BSH 8     // 256 nodes per bucket
#define CAP 8192  // edge capacity per bucket (mean 4096 at E=1.6M, NB=391)
#define BCHUNK 4096
#define CAPD 64   // adjacency slots per node (deg~Poisson(16); P(deg>64)~1e-19/node)
// requires N <= 131072 (src fits 24 bits after <<8 shift; bucket count <= 512)

__device__ __forceinline__ float bflo(unsigned int v) { return __uint_as_float(v << 16); }
__device__ __forceinline__ float bfhi(unsigned int v) { return __uint_as_float(v & 0xffff0000u); }
__device__ __forceinline__ unsigned int packbf2(float a, float b) {
    __hip_bfloat162 p; p.x = __float2bfloat16(a); p.y = __float2bfloat16(b);
    return *(unsigned int*)&p;
}

// ---- bin edges by dst bucket via per-chunk LDS counting sort; coalesced writes ----
__global__ __launch_bounds__(512) void bin_edges(
    const int* __restrict__ src, const int* __restrict__ dst,
    int* __restrict__ cursor, int* __restrict__ binned, int E, int NB)
{
    __shared__ int vals[BCHUNK];
    __shared__ unsigned short bkts[BCHUNK];
    __shared__ int svals[BCHUNK];
    __shared__ unsigned short sbkt[BCHUNK];
    __shared__ int scnt[512];
    __shared__ int sex[512];
    __shared__ int lcur[512];
    __shared__ int gbase[512];
    __shared__ int wsum[8];

    int tid = threadIdx.x;
    scnt[tid] = 0;
    __syncthreads();

    int e0 = blockIdx.x * BCHUNK;
    int n = min(e0 + BCHUNK, E) - e0;

    for (int i = tid; i < n; i += 512) {
        int d = dst[e0 + i];
        int b = d >> BSH;
        vals[i] = (src[e0 + i] << BSH) | (d & 255);
        bkts[i] = (unsigned short)b;
        atomicAdd(&scnt[b], 1);
    }
    __syncthreads();

    int c = scnt[tid];
    int lane = tid & 63, w = tid >> 6;
    int v = c;
#pragma unroll
    for (int off = 1; off < 64; off <<= 1) {
        int t = __shfl_up(v, off, 64);
        if (lane >= off) v += t;
    }
    if (lane == 63) wsum[w] = v;
    __syncthreads();
    int wbase = 0;
    for (int k = 0; k < w; k++) wbase += wsum[k];
    int ex = v + wbase - c;
    sex[tid] = ex;
    lcur[tid] = ex;
    if (c) gbase[tid] = tid * CAP + atomicAdd(&cursor[tid], c);
    __syncthreads();

    for (int i = tid; i < n; i += 512) {
        int b = bkts[i];
        int p = atomicAdd(&lcur[b], 1);
        svals[p] = vals[i];
        sbkt[p] = (unsigned short)b;
    }
    __syncthreads();

    for (int i = tid; i < n; i += 512) {
        int b = sbkt[i];
        binned[gbase[b] + (i - sex[b])] = svals[i];
    }
}

// ---- per-bucket adjacency build: LDS scatter, fully coalesced global write ----
__global__ __launch_bounds__(512) void bucket_adj(
    const int* __restrict__ cursor, const int* __restrict__ binned,
    int* __restrict__ rowcnt, int* __restrict__ adj, int N)
{
    __shared__ int cnt[256];
    __shared__ int ladj[256 * CAPD];   // 64 KB
    int b = blockIdx.x, tid = threadIdx.x;
    int bn = b << BSH;
    if (tid < 256) cnt[tid] = 0;
    __syncthreads();
    int es = b * CAP, ee = es + cursor[b];
    for (int i = es + tid; i < ee; i += 512) {
        int e = binned[i];
        int d = e & 255;
        int slot = atomicAdd(&cnt[d], 1);
        if (slot < CAPD) ladj[(d << 6) + slot] = e >> BSH;
    }
    __syncthreads();
    int gb = bn * CAPD;
    for (int j = tid; j < 256 * CAPD; j += 512) adj[gb + j] = ladj[j];
    if (tid < 256) {
        int nn = bn + tid;
        if (nn < N) rowcnt[nn] = cnt[tid];
    }
}

// ---- embed + ALL node-local products ----
__global__ __launch_bounds__(256) void embed_g1(
    const float* __restrict__ x, const float* __restrict__ We,
    const float* __restrict__ be, const float* __restrict__ W1,
    const float* __restrict__ W2, const float* __restrict__ Wp,
    const float* __restrict__ bp, const int* __restrict__ rowcnt,
    __hip_bfloat16* __restrict__ g, __hip_bfloat16* __restrict__ y2,
    float* __restrict__ hp, int N)
{
    __shared__ float sWe[NF * H];
    __shared__ float sW1[H * H];
    __shared__ float sW2b[H * H];
    __shared__ float sbe[H];
    __shared__ float sWpb[H];
    __shared__ float sx[8][NF];
    __shared__ float sh[8][H];

    int tid = threadIdx.x;
    for (int j = tid; j < NF * H; j += 256) sWe[j] = We[j];
    for (int j = tid; j < H * H; j += 256) sW1[j] = W1[j];
    for (int j = tid; j < H * H; j += 256) sW2b[j] = W2[H * H + j];
    if (tid < H) sbe[tid] = be[tid];
    if (tid >= H && tid < 2 * H) sWpb[tid - H] = Wp[tid];

    int grp = tid >> 5, t = tid & 31;
    int ngrp = (N + 7) >> 3;
    for (int nb = blockIdx.x; nb < ngrp; nb += gridDim.x) {
        int node = nb * 8 + grp;
        int nodec = node < N ? node : N - 1;
        __syncthreads();
        if (t < NF) sx[grp][t] = x[(size_t)nodec * NF + t];
        __syncthreads();

        float h = sbe[t];
#pragma unroll
        for (int k = 0; k < NF; k++) h += sx[grp][k] * sWe[k * H + t];
        sh[grp][t] = h;
        __syncthreads();

        float di = rsqrtf((float)(rowcnt[nodec] + 1));
        float gv = 0.f, yv = 0.f;
#pragma unroll
        for (int k = 0; k < H; k++) {
            float hv = sh[grp][k];
            gv += hv * sW1[k * H + t];
            yv += hv * sW2b[k * H + t];
        }
        gv *= di;

        float pv = h * sWpb[t];
#pragma unroll
        for (int off = 16; off > 0; off >>= 1) pv += __shfl_down(pv, off, 32);

        if (node < N) {
            size_t o = (size_t)node * H + t;
            g[o] = __float2bfloat16(gv);
            y2[o] = __float2bfloat16(yv);
            if (t == 0) hp[node] = pv + bp[0] + sx[grp][1];
        }
    }
}

// ---- fused gather #1 + mid layer, 8 lanes/node, uint2 (4 bf16) loads ----
__global__ __launch_bounds__(256) void agg_mid(
    const int* __restrict__ rowcnt, const int* __restrict__ adj,
    const __hip_bfloat16* __restrict__ g_in, const __hip_bfloat16* __restrict__ y2,
    const float* __restrict__ W2, const float* __restrict__ b1,
    __hip_bfloat16* __restrict__ g_out, int N)
{
    __shared__ float sW2[H * H];     // W2 rows 0..31
    __shared__ float srow[32][33];

    int tid = threadIdx.x;
    for (int j = tid; j < H * H; j += 256) sW2[j] = W2[j];

    int grp = tid >> 3, lane = tid & 7;   // 32 nodes/block, 8 lanes/node
    int node = blockIdx.x * 32 + grp;
    int nodec = node < N ? node : N - 1;

    const uint2* gv2 = (const uint2*)g_in;   // row = 8 uint2
    uint2 sv = gv2[(size_t)nodec * 8 + lane];
    float a0 = bflo(sv.x), a1 = bfhi(sv.x), a2 = bflo(sv.y), a3 = bfhi(sv.y);

    int rc = rowcnt[nodec];
    int cnt = rc < CAPD ? rc : CAPD;
    int start = nodec * CAPD;
    int end = start + cnt;
    int i = start;
    for (; i + 7 < end; i += 8) {
        int4 sa = *(const int4*)(adj + i);
        int4 sb = *(const int4*)(adj + i + 4);
        uint2 v0 = gv2[(size_t)sa.x * 8 + lane], v1 = gv2[(size_t)sa.y * 8 + lane];
        uint2 v2 = gv2[(size_t)sa.z * 8 + lane], v3 = gv2[(size_t)sa.w * 8 + lane];
        uint2 v4 = gv2[(size_t)sb.x * 8 + lane], v5 = gv2[(size_t)sb.y * 8 + lane];
        uint2 v6 = gv2[(size_t)sb.z * 8 + lane], v7 = gv2[(size_t)sb.w * 8 + lane];
        a0 += bflo(v0.x) + bflo(v1.x) + bflo(v2.x) + bflo(v3.x)
            + bflo(v4.x) + bflo(v5.x) + bflo(v6.x) + bflo(v7.x);
        a1 += bfhi(v0.x) + bfhi(v1.x) + bfhi(v2.x) + bfhi(v3.x)
            + bfhi(v4.x) + bfhi(v5.x) + bfhi(v6.x) + bfhi(v7.x);
        a2 += bflo(v0.y) + bflo(v1.y) + bflo(v2.y) + bflo(v3.y)
            + bflo(v4.y) + bflo(v5.y) + bflo(v6.y) + bflo(v7.y);
        a3 += bfhi(v0.y) + bfhi(v1.y) + bfhi(v2.y) + bfhi(v3.y)
            + bfhi(v4.y) + bfhi(v5.y) + bfhi(v6.y) + bfhi(v7.y);
    }
    if (i < end) {   // predicated tail octet (1..7 valid edges)
        unsigned nm1 = (unsigned)(N - 1);
        int4 sa = *(const int4*)(adj + i);
        int4 sb = *(const int4*)(adj + i + 4);
        int s0 = sa.x;
        int s1 = (int)min((unsigned)sa.y, nm1), s2 = (int)min((unsigned)sa.z, nm1);
        int s3 = (int)min((unsigned)sa.w, nm1), s4 = (int)min((unsigned)sb.x, nm1);
        int s5 = (int)min((unsigned)sb.y, nm1), s6 = (int)min((unsigned)sb.z, nm1);
        int s7 = (int)min((unsigned)sb.w, nm1);
        uint2 v0 = gv2[(size_t)s0 * 8 + lane], v1 = gv2[(size_t)s1 * 8 + lane];
        uint2 v2 = gv2[(size_t)s2 * 8 + lane], v3 = gv2[(size_t)s3 * 8 + lane];
        uint2 v4 = gv2[(size_t)s4 * 8 + lane], v5 = gv2[(size_t)s5 * 8 + lane];
        uint2 v6 = gv2[(size_t)s6 * 8 + lane], v7 = gv2[(size_t)s7 * 8 + lane];
        if (i + 1 >= end) { v1.x = 0u; v1.y = 0u; }
        if (i + 2 >= end) { v2.x = 0u; v2.y = 0u; }
        if (i + 3 >= end) { v3.x = 0u; v3.y = 0u; }
        if (i + 4 >= end) { v4.x = 0u; v4.y = 0u; }
        if (i + 5 >= end) { v5.x = 0u; v5.y = 0u; }
        if (i + 6 >= end) { v6.x = 0u; v6.y = 0u; }
        if (i + 7 >= end) { v7.x = 0u; v7.y = 0u; }
        a0 += bflo(v0.x) + bflo(v1.x) + bflo(v2.x) + bflo(v3.x)
            + bflo(v4.x) + bflo(v5.x) + bflo(v6.x) + bflo(v7.x);
        a1 += bfhi(v0.x) + bfhi(v1.x) + bfhi(v2.x) + bfhi(v3.x)
            + bfhi(v4.x) + bfhi(v5.x) + bfhi(v6.x) + bfhi(v7.x);
        a2 += bflo(v0.y) + bflo(v1.y) + bflo(v2.y) + bflo(v3.y)
            + bflo(v4.y) + bflo(v5.y) + bflo(v6.y) + bflo(v7.y);
        a3 += bfhi(v0.y) + bfhi(v1.y) + bfhi(v2.y) + bfhi(v3.y)
            + bfhi(v4.y) + bfhi(v5.y) + bfhi(v6.y) + bfhi(v7.y);
    }

    float di = rsqrtf((float)(rc + 1));
    float4 bb = ((const float4*)b1)[lane];
    srow[grp][4 * lane]     = fmaxf(di * a0 + bb.x, 0.f);
    srow[grp][4 * lane + 1] = fmaxf(di * a1 + bb.y, 0.f);
    srow[grp][4 * lane + 2] = fmaxf(di * a2 + bb.z, 0.f);
    srow[grp][4 * lane + 3] = fmaxf(di * a3 + bb.w, 0.f);
    __syncthreads();   // covers sW2 staging AND srow writes

    const float4* sW2v = (const float4*)sW2;
    float o0 = 0.f, o1 = 0.f, o2 = 0.f, o3 = 0.f;
#pragma unroll
    for (int k = 0; k < H; k++) {
        float rv = srow[grp][k];           // broadcast within group
        float4 w = sW2v[k * 8 + lane];
        o0 += rv * w.x; o1 += rv * w.y; o2 += rv * w.z; o3 += rv * w.w;
    }
    uint2 yv = ((const uint2*)y2)[(size_t)nodec * 8 + lane];
    o0 = di * (o0 + bflo(yv.x));
    o1 = di * (o1 + bfhi(yv.x));
    o2 = di * (o2 + bflo(yv.y));
    o3 = di * (o3 + bfhi(yv.y));

    if (node < N) {
        uint2 p;
        p.x = packbf2(o0, o1);
        p.y = packbf2(o2, o3);
        ((uint2*)g_out)[(size_t)node * 8 + lane] = p;
    }
}

// ---- fused gather #2 + prediction head, 8 lanes/node ----
__global__ __launch_bounds__(256) void agg_final(
    const int* __restrict__ rowcnt, const int* __restrict__ adj,
    const __hip_bfloat16* __restrict__ g_in, const float* __restrict__ hp,
    const float* __restrict__ b2, const float* __restrict__ Wp,
    float* __restrict__ out, int N)
{
    int gid = blockIdx.x * blockDim.x + threadIdx.x;
    int node = gid >> 3;
    if (node >= N) return;
    int lane = gid & 7;

    const uint2* gv2 = (const uint2*)g_in;
    uint2 sv = gv2[(size_t)node * 8 + lane];
    float a0 = bflo(sv.x), a1 = bfhi(sv.x), a2 = bflo(sv.y), a3 = bfhi(sv.y);

    int rc = rowcnt[node];
    int cnt = rc < CAPD ? rc : CAPD;
    int start = node * CAPD;
    int end = start + cnt;
    int i = start;
    for (; i + 7 < end; i += 8) {
        int4 sa = *(const int4*)(adj + i);
        int4 sb = *(const int4*)(adj + i + 4);
        uint2 v0 = gv2[(size_t)sa.x * 8 + lane], v1 = gv2[(size_t)sa.y * 8 + lane];
        uint2 v2 = gv2[(size_t)sa.z * 8 + lane], v3 = gv2[(size_t)sa.w * 8 + lane];
        uint2 v4 = gv2[(size_t)sb.x * 8 + lane], v5 = gv2[(size_t)sb.y * 8 + lane];
        uint2 v6 = gv2[(size_t)sb.z * 8 + lane], v7 = gv2[(size_t)sb.w * 8 + lane];
        a0 += bflo(v0.x) + bflo(v1.x) + bflo(v2.x) + bflo(v3.x)
            + bflo(v4.x) + bflo(v5.x) + bflo(v6.x) + bflo(v7.x);
        a1 += bfhi(v0.x) + bfhi(v1.x) + bfhi(v2.x) + bfhi(v3.x)
            + bfhi(v4.x) + bfhi(v5.x) + bfhi(v6.x) + bfhi(v7.x);
        a2 += bflo(v0.y) + bflo(v1.y) + bflo(v2.y) + bflo(v3.y)
            + bflo(v4.y) + bflo(v5.y) + bflo(v6.y) + bflo(v7.y);
        a3 += bfhi(v0.y) + bfhi(v1.y) + bfhi(v2.y) + bfhi(v3.y)
            + bfhi(v4.y) + bfhi(v5.y) + bfhi(v6.y) + bfhi(v7.y);
    }
    if (i < end) {   // predicated tail octet
        unsigned nm1 = (unsigned)(N - 1);
        int4 sa = *(const int4*)(adj + i);
        int4 sb = *(const int4*)(adj + i + 4);
        int s0 = sa.x;
        int s1 = (int)min((unsigned)sa.y, nm1), s2 = (int)min((unsigned)sa.z, nm1);
        int s3 = (int)min((unsigned)sa.w, nm1), s4 = (int)min((unsigned)sb.x, nm1);
        int s5 = (int)min((unsigned)sb.y, nm1), s6 = (int)min((unsigned)sb.z, nm1);
        int s7 = (int)min((unsigned)sb.w, nm1);
        uint2 v0 = gv2[(size_t)s0 * 8 + lane], v1 = gv2[(size_t)s1 * 8 + lane];
        uint2 v2 = gv2[(size_t)s2 * 8 + lane], v3 = gv2[(size_t)s3 * 8 + lane];
        uint2 v4 = gv2[(size_t)s4 * 8 + lane], v5 = gv2[(size_t)s5 * 8 + lane];
        uint2 v6 = gv2[(size_t)s6 * 8 + lane], v7 = gv2[(size_t)s7 * 8 + lane];
        if (i + 1 >= end) { v1.x = 0u; v1.y = 0u; }
        if (i + 2 >= end) { v2.x = 0u; v2.y = 0u; }
        if (i + 3 >= end) { v3.x = 0u; v3.y = 0u; }
        if (i + 4 >= end) { v4.x = 0u; v4.y = 0u; }
        if (i + 5 >= end) { v5.x = 0u; v5.y = 0u; }
        if (i + 6 >= end) { v6.x = 0u; v6.y = 0u; }
        if (i + 7 >= end) { v7.x = 0u; v7.y = 0u; }
        a0 += bflo(v0.x) + bflo(v1.x) + bflo(v2.x) + bflo(v3.x)
            + bflo(v4.x) + bflo(v5.x) + bflo(v6.x) + bflo(v7.x);
        a1 += bfhi(v0.x) + bfhi(v1.x) + bfhi(v2.x) + bfhi(v3.x)
            + bfhi(v4.x) + bfhi(v5.x) + bfhi(v6.x) + bfhi(v7.x);
        a2 += bflo(v0.y) + bflo(v1.y) + bflo(v2.y) + bflo(v3.y)
            + bflo(v4.y) + bflo(v5.y) + bflo(v6.y) + bflo(v7.y);
        a3 += bfhi(v0.y) + bfhi(v1.y) + bfhi(v2.y) + bfhi(v3.y)
            + bfhi(v4.y) + bfhi(v5.y) + bfhi(v6.y) + bfhi(v7.y);
    }

    float di = rsqrtf((float)(rc + 1));
    float4 b2v = ((const float4*)b2)[lane];
    float4 wp  = ((const float4*)Wp)[lane];
    float v = fmaxf(di * a0 + b2v.x, 0.f) * wp.x
            + fmaxf(di * a1 + b2v.y, 0.f) * wp.y
            + fmaxf(di * a2 + b2v.z, 0.f) * wp.z
            + fmaxf(di * a3 + b2v.w, 0.f) * wp.w;
#pragma unroll
    for (int off = 4; off > 0; off >>= 1) v += __shfl_down(v, off, 8);
    if (lane == 0) out[node] = fmaxf(v + hp[node], 0.f);
}

extern "C" void kernel_launch(void* const* d_in, const int* in_sizes, int n_in,
                              void* d_out, int out_size, void* d_ws, size_t ws_size,
                              hipStream_t stream) {
    const float* x  = (const float*)d_in[0];
    const int*   ei = (const int*)d_in[1];
    const float* We = (const float*)d_in[2];
    const float* be = (const float*)d_in[3];
    const float* W1 = (const float*)d_in[4];
    const float* b1 = (const float*)d_in[5];
    const float* W2 = (const float*)d_in[6];
    const float* b2 = (const float*)d_in[7];
    const float* Wp = (const float*)d_in[8];
    const float* bp = (const float*)d_in[9];
    float* out = (float*)d_out;

    const int N = in_sizes[0] / NF;
    const int E = in_sizes[1] / 2;
    const int* src = ei;
    const int* dst = ei + E;
    const int NB = (N + 255) >> BSH;                // 391
    const int nchunk = (E + BCHUNK - 1) / BCHUNK;   // 391

    size_t Np  = ((size_t)N + 127) & ~(size_t)127;
    size_t NHp = ((size_t)N * H + 127) & ~(size_t)127;
    float* ws  = (float*)d_ws;
    float* hp  = ws;                                   // Np
    __hip_bfloat16* g1 = (__hip_bfloat16*)(hp + Np);   // NHp bf16
    __hip_bfloat16* g2 = g1 + NHp;                     // NHp bf16
    __hip_bfloat16* y2 = g2 + NHp;                     // NHp bf16
    int* cursor  = (int*)(y2 + NHp);                   // 512
    int* cursor2 = cursor + 512;                       // 512 (probe scratch)
    int* rowcnt  = cursor2 + 512;                      // Np
    int* binned  = rowcnt + Np;                        // NB*CAP
    int* adj     = binned + (size_t)NB * CAP;          // Np*CAPD
    int* binned2 = adj + Np * CAPD;                    // NB*CAP (probe scratch)

    (void)hipMemsetAsync(cursor, 0, 1024 * sizeof(int), stream);  // cursor + cursor2
    bin_edges<<<nchunk, 512, 0, stream>>>(src, dst, cursor, binned, E, NB);
    // PROBE: bin_edges is a pure function of (src,dst)->(cursor,binned); two extra
    // launches into scratch buffers leave the real pipeline untouched.
    // dur delta vs single launch = 2 * t_bin_edges.
    bin_edges<<<nchunk, 512, 0, stream>>>(src, dst, cursor2, binned2, E, NB);
    bin_edges<<<nchunk, 512, 0, stream>>>(src, dst, cursor2, binned2, E, NB);
    bucket_adj<<<NB, 512, 0, stream>>>(cursor, binned, rowcnt, adj, N);

    int ngrp = (N + 7) >> 3;
    int eg = ngrp < 1536 ? ngrp : 1536;
    embed_g1<<<eg, 256, 0, stream>>>(x, We, be, W1, W2, Wp, bp, rowcnt, g1, y2, hp, N);
    agg_mid<<<(N + 31) / 32, 256, 0, stream>>>(rowcnt, adj, g1, y2, W2, b1, g2, N);
    agg_final<<<((size_t)N * 8 + 255) / 256, 256, 0, stream>>>(rowcnt, adj, g2, hp, b2, Wp, out, N);
}

// Round 11
// 188.051 us; speedup vs baseline: 4.4145x; 1.1573x over previous
//
#include <hip/hip_runtime.h>
#include <hip/hip_bf16.h>

#define NF 22     // node features
#define H  32     // hidden dim
#define BSH 8     // 256 nodes per bucket
#define CAP 8192  // edge capacity per bucket (mean 4096 at E=1.6M, NB=391)
#define BCHUNK 4096
#define CAPD 64   // adjacency slots per node (deg~Poisson(16); P(deg>64)~1e-19/node)
// requires N <= 131072 (src fits 24 bits after <<8 shift; bucket count <= 512)

__device__ __forceinline__ float bflo(unsigned int v) { return __uint_as_float(v << 16); }
__device__ __forceinline__ float bfhi(unsigned int v) { return __uint_as_float(v & 0xffff0000u); }
__device__ __forceinline__ unsigned int packbf2(float a, float b) {
    __hip_bfloat162 p; p.x = __float2bfloat16(a); p.y = __float2bfloat16(b);
    return *(unsigned int*)&p;
}

// ---- bin edges by dst bucket via per-chunk LDS counting sort; coalesced writes ----
__global__ __launch_bounds__(512) void bin_edges(
    const int* __restrict__ src, const int* __restrict__ dst,
    int* __restrict__ cursor, int* __restrict__ binned, int E, int NB)
{
    __shared__ int vals[BCHUNK];
    __shared__ unsigned short bkts[BCHUNK];
    __shared__ int svals[BCHUNK];
    __shared__ unsigned short sbkt[BCHUNK];
    __shared__ int scnt[512];
    __shared__ int sex[512];
    __shared__ int lcur[512];
    __shared__ int gbase[512];
    __shared__ int wsum[8];

    int tid = threadIdx.x;
    scnt[tid] = 0;
    __syncthreads();

    int e0 = blockIdx.x * BCHUNK;
    int n = min(e0 + BCHUNK, E) - e0;

    for (int i = tid; i < n; i += 512) {
        int d = dst[e0 + i];
        int b = d >> BSH;
        vals[i] = (src[e0 + i] << BSH) | (d & 255);
        bkts[i] = (unsigned short)b;
        atomicAdd(&scnt[b], 1);
    }
    __syncthreads();

    int c = scnt[tid];
    int lane = tid & 63, w = tid >> 6;
    int v = c;
#pragma unroll
    for (int off = 1; off < 64; off <<= 1) {
        int t = __shfl_up(v, off, 64);
        if (lane >= off) v += t;
    }
    if (lane == 63) wsum[w] = v;
    __syncthreads();
    int wbase = 0;
    for (int k = 0; k < w; k++) wbase += wsum[k];
    int ex = v + wbase - c;
    sex[tid] = ex;
    lcur[tid] = ex;
    if (c) gbase[tid] = tid * CAP + atomicAdd(&cursor[tid], c);
    __syncthreads();

    for (int i = tid; i < n; i += 512) {
        int b = bkts[i];
        int p = atomicAdd(&lcur[b], 1);
        svals[p] = vals[i];
        sbkt[p] = (unsigned short)b;
    }
    __syncthreads();

    for (int i = tid; i < n; i += 512) {
        int b = sbkt[i];
        binned[gbase[b] + (i - sex[b])] = svals[i];
    }
}

// ---- per-bucket adjacency build: LDS scatter, coalesced trimmed global write ----
// Writes only ms = pow2-rounded max-degree columns (32 for ~97% of buckets).
// Agg reads never exceed ceil(cnt/8)*8 <= ms columns (ms multiple of 8), all written.
__global__ __launch_bounds__(512) void bucket_adj(
    const int* __restrict__ cursor, const int* __restrict__ binned,
    int* __restrict__ rowcnt, int* __restrict__ adj, int N)
{
    __shared__ int cnt[256];
    __shared__ int ladj[256 * CAPD];   // 64 KB
    __shared__ int bmax_sh;
    int b = blockIdx.x, tid = threadIdx.x;
    int bn = b << BSH;
    if (tid < 256) cnt[tid] = 0;
    if (tid == 0) bmax_sh = 0;
    __syncthreads();
    int es = b * CAP, ee = es + cursor[b];
    for (int i = es + tid; i < ee; i += 512) {
        int e = binned[i];
        int d = e & 255;
        int slot = atomicAdd(&cnt[d], 1);
        if (slot < CAPD) ladj[(d << 6) + slot] = e >> BSH;
    }
    __syncthreads();
    if (tid < 256) atomicMax(&bmax_sh, cnt[tid]);
    __syncthreads();
    int sh = (bmax_sh <= 32) ? 5 : 6;      // ms = 32 or 64 columns
    int ms1 = (1 << sh) - 1;
    int gb = bn * CAPD;
    for (int j = tid; j < (256 << sh); j += 512) {
        int node = j >> sh, slot = j & ms1;
        adj[gb + (node << 6) + slot] = ladj[(node << 6) + slot];
    }
    if (tid < 256) {
        int nn = bn + tid;
        if (nn < N) rowcnt[nn] = cnt[tid];
    }
}

// ---- embed + ALL node-local products ----
__global__ __launch_bounds__(256) void embed_g1(
    const float* __restrict__ x, const float* __restrict__ We,
    const float* __restrict__ be, const float* __restrict__ W1,
    const float* __restrict__ W2, const float* __restrict__ Wp,
    const float* __restrict__ bp, const int* __restrict__ rowcnt,
    __hip_bfloat16* __restrict__ g, __hip_bfloat16* __restrict__ y2,
    float* __restrict__ hp, int N)
{
    __shared__ float sWe[NF * H];
    __shared__ float sW1[H * H];
    __shared__ float sW2b[H * H];
    __shared__ float sbe[H];
    __shared__ float sWpb[H];
    __shared__ float sx[8][NF];
    __shared__ float sh[8][H];

    int tid = threadIdx.x;
    for (int j = tid; j < NF * H; j += 256) sWe[j] = We[j];
    for (int j = tid; j < H * H; j += 256) sW1[j] = W1[j];
    for (int j = tid; j < H * H; j += 256) sW2b[j] = W2[H * H + j];
    if (tid < H) sbe[tid] = be[tid];
    if (tid >= H && tid < 2 * H) sWpb[tid - H] = Wp[tid];

    int grp = tid >> 5, t = tid & 31;
    int ngrp = (N + 7) >> 3;
    for (int nb = blockIdx.x; nb < ngrp; nb += gridDim.x) {
        int node = nb * 8 + grp;
        int nodec = node < N ? node : N - 1;
        __syncthreads();
        if (t < NF) sx[grp][t] = x[(size_t)nodec * NF + t];
        __syncthreads();

        float h = sbe[t];
#pragma unroll
        for (int k = 0; k < NF; k++) h += sx[grp][k] * sWe[k * H + t];
        sh[grp][t] = h;
        __syncthreads();

        float di = rsqrtf((float)(rowcnt[nodec] + 1));
        float gv = 0.f, yv = 0.f;
#pragma unroll
        for (int k = 0; k < H; k++) {
            float hv = sh[grp][k];
            gv += hv * sW1[k * H + t];
            yv += hv * sW2b[k * H + t];
        }
        gv *= di;

        float pv = h * sWpb[t];
#pragma unroll
        for (int off = 16; off > 0; off >>= 1) pv += __shfl_down(pv, off, 32);

        if (node < N) {
            size_t o = (size_t)node * H + t;
            g[o] = __float2bfloat16(gv);
            y2[o] = __float2bfloat16(yv);
            if (t == 0) hp[node] = pv + bp[0] + sx[grp][1];
        }
    }
}

// ---- fused gather #1 + mid layer, 8 lanes/node, uint2 (4 bf16) loads ----
__global__ __launch_bounds__(256) void agg_mid(
    const int* __restrict__ rowcnt, const int* __restrict__ adj,
    const __hip_bfloat16* __restrict__ g_in, const __hip_bfloat16* __restrict__ y2,
    const float* __restrict__ W2, const float* __restrict__ b1,
    __hip_bfloat16* __restrict__ g_out, int N)
{
    __shared__ float sW2[H * H];     // W2 rows 0..31
    __shared__ float srow[32][33];

    int tid = threadIdx.x;
    for (int j = tid; j < H * H; j += 256) sW2[j] = W2[j];

    int grp = tid >> 3, lane = tid & 7;   // 32 nodes/block, 8 lanes/node
    int node = blockIdx.x * 32 + grp;
    int nodec = node < N ? node : N - 1;

    const uint2* gv2 = (const uint2*)g_in;   // row = 8 uint2
    uint2 sv = gv2[(size_t)nodec * 8 + lane];
    float a0 = bflo(sv.x), a1 = bfhi(sv.x), a2 = bflo(sv.y), a3 = bfhi(sv.y);

    int rc = rowcnt[nodec];
    int cnt = rc < CAPD ? rc : CAPD;
    int start = nodec * CAPD;
    int end = start + cnt;
    int i = start;
    for (; i + 7 < end; i += 8) {
        int4 sa = *(const int4*)(adj + i);
        int4 sb = *(const int4*)(adj + i + 4);
        uint2 v0 = gv2[(size_t)sa.x * 8 + lane], v1 = gv2[(size_t)sa.y * 8 + lane];
        uint2 v2 = gv2[(size_t)sa.z * 8 + lane], v3 = gv2[(size_t)sa.w * 8 + lane];
        uint2 v4 = gv2[(size_t)sb.x * 8 + lane], v5 = gv2[(size_t)sb.y * 8 + lane];
        uint2 v6 = gv2[(size_t)sb.z * 8 + lane], v7 = gv2[(size_t)sb.w * 8 + lane];
        a0 += bflo(v0.x) + bflo(v1.x) + bflo(v2.x) + bflo(v3.x)
            + bflo(v4.x) + bflo(v5.x) + bflo(v6.x) + bflo(v7.x);
        a1 += bfhi(v0.x) + bfhi(v1.x) + bfhi(v2.x) + bfhi(v3.x)
            + bfhi(v4.x) + bfhi(v5.x) + bfhi(v6.x) + bfhi(v7.x);
        a2 += bflo(v0.y) + bflo(v1.y) + bflo(v2.y) + bflo(v3.y)
            + bflo(v4.y) + bflo(v5.y) + bflo(v6.y) + bflo(v7.y);
        a3 += bfhi(v0.y) + bfhi(v1.y) + bfhi(v2.y) + bfhi(v3.y)
            + bfhi(v4.y) + bfhi(v5.y) + bfhi(v6.y) + bfhi(v7.y);
    }
    if (i < end) {   // predicated tail octet (1..7 valid edges)
        unsigned nm1 = (unsigned)(N - 1);
        int4 sa = *(const int4*)(adj + i);
        int4 sb = *(const int4*)(adj + i + 4);
        int s0 = sa.x;
        int s1 = (int)min((unsigned)sa.y, nm1), s2 = (int)min((unsigned)sa.z, nm1);
        int s3 = (int)min((unsigned)sa.w, nm1), s4 = (int)min((unsigned)sb.x, nm1);
        int s5 = (int)min((unsigned)sb.y, nm1), s6 = (int)min((unsigned)sb.z, nm1);
        int s7 = (int)min((unsigned)sb.w, nm1);
        uint2 v0 = gv2[(size_t)s0 * 8 + lane], v1 = gv2[(size_t)s1 * 8 + lane];
        uint2 v2 = gv2[(size_t)s2 * 8 + lane], v3 = gv2[(size_t)s3 * 8 + lane];
        uint2 v4 = gv2[(size_t)s4 * 8 + lane], v5 = gv2[(size_t)s5 * 8 + lane];
        uint2 v6 = gv2[(size_t)s6 * 8 + lane], v7 = gv2[(size_t)s7 * 8 + lane];
        if (i + 1 >= end) { v1.x = 0u; v1.y = 0u; }
        if (i + 2 >= end) { v2.x = 0u; v2.y = 0u; }
        if (i + 3 >= end) { v3.x = 0u; v3.y = 0u; }
        if (i + 4 >= end) { v4.x = 0u; v4.y = 0u; }
        if (i + 5 >= end) { v5.x = 0u; v5.y = 0u; }
        if (i + 6 >= end) { v6.x = 0u; v6.y = 0u; }
        if (i + 7 >= end) { v7.x = 0u; v7.y = 0u; }
        a0 += bflo(v0.x) + bflo(v1.x) + bflo(v2.x) + bflo(v3.x)
            + bflo(v4.x) + bflo(v5.x) + bflo(v6.x) + bflo(v7.x);
        a1 += bfhi(v0.x) + bfhi(v1.x) + bfhi(v2.x) + bfhi(v3.x)
            + bfhi(v4.x) + bfhi(v5.x) + bfhi(v6.x) + bfhi(v7.x);
        a2 += bflo(v0.y) + bflo(v1.y) + bflo(v2.y) + bflo(v3.y)
            + bflo(v4.y) + bflo(v5.y) + bflo(v6.y) + bflo(v7.y);
        a3 += bfhi(v0.y) + bfhi(v1.y) + bfhi(v2.y) + bfhi(v3.y)
            + bfhi(v4.y) + bfhi(v5.y) + bfhi(v6.y) + bfhi(v7.y);
    }

    float di = rsqrtf((float)(rc + 1));
    float4 bb = ((const float4*)b1)[lane];
    srow[grp][4 * lane]     = fmaxf(di * a0 + bb.x, 0.f);
    srow[grp][4 * lane + 1] = fmaxf(di * a1 + bb.y, 0.f);
    srow[grp][4 * lane + 2] = fmaxf(di * a2 + bb.z, 0.f);
    srow[grp][4 * lane + 3] = fmaxf(di * a3 + bb.w, 0.f);
    __syncthreads();   // covers sW2 staging AND srow writes

    const float4* sW2v = (const float4*)sW2;
    float o0 = 0.f, o1 = 0.f, o2 = 0.f, o3 = 0.f;
#pragma unroll
    for (int k = 0; k < H; k++) {
        float rv = srow[grp][k];           // broadcast within group
        float4 w = sW2v[k * 8 + lane];
        o0 += rv * w.x; o1 += rv * w.y; o2 += rv * w.z; o3 += rv * w.w;
    }
    uint2 yv = ((const uint2*)y2)[(size_t)nodec * 8 + lane];
    o0 = di * (o0 + bflo(yv.x));
    o1 = di * (o1 + bfhi(yv.x));
    o2 = di * (o2 + bflo(yv.y));
    o3 = di * (o3 + bfhi(yv.y));

    if (node < N) {
        uint2 p;
        p.x = packbf2(o0, o1);
        p.y = packbf2(o2, o3);
        ((uint2*)g_out)[(size_t)node * 8 + lane] = p;
    }
}

// ---- fused gather #2 + prediction head, 8 lanes/node ----
__global__ __launch_bounds__(256) void agg_final(
    const int* __restrict__ rowcnt, const int* __restrict__ adj,
    const __hip_bfloat16* __restrict__ g_in, const float* __restrict__ hp,
    const float* __restrict__ b2, const float* __restrict__ Wp,
    float* __restrict__ out, int N)
{
    int gid = blockIdx.x * blockDim.x + threadIdx.x;
    int node = gid >> 3;
    if (node >= N) return;
    int lane = gid & 7;

    const uint2* gv2 = (const uint2*)g_in;
    uint2 sv = gv2[(size_t)node * 8 + lane];
    float a0 = bflo(sv.x), a1 = bfhi(sv.x), a2 = bflo(sv.y), a3 = bfhi(sv.y);

    int rc = rowcnt[node];
    int cnt = rc < CAPD ? rc : CAPD;
    int start = node * CAPD;
    int end = start + cnt;
    int i = start;
    for (; i + 7 < end; i += 8) {
        int4 sa = *(const int4*)(adj + i);
        int4 sb = *(const int4*)(adj + i + 4);
        uint2 v0 = gv2[(size_t)sa.x * 8 + lane], v1 = gv2[(size_t)sa.y * 8 + lane];
        uint2 v2 = gv2[(size_t)sa.z * 8 + lane], v3 = gv2[(size_t)sa.w * 8 + lane];
        uint2 v4 = gv2[(size_t)sb.x * 8 + lane], v5 = gv2[(size_t)sb.y * 8 + lane];
        uint2 v6 = gv2[(size_t)sb.z * 8 + lane], v7 = gv2[(size_t)sb.w * 8 + lane];
        a0 += bflo(v0.x) + bflo(v1.x) + bflo(v2.x) + bflo(v3.x)
            + bflo(v4.x) + bflo(v5.x) + bflo(v6.x) + bflo(v7.x);
        a1 += bfhi(v0.x) + bfhi(v1.x) + bfhi(v2.x) + bfhi(v3.x)
            + bfhi(v4.x) + bfhi(v5.x) + bfhi(v6.x) + bfhi(v7.x);
        a2 += bflo(v0.y) + bflo(v1.y) + bflo(v2.y) + bflo(v3.y)
            + bflo(v4.y) + bflo(v5.y) + bflo(v6.y) + bflo(v7.y);
        a3 += bfhi(v0.y) + bfhi(v1.y) + bfhi(v2.y) + bfhi(v3.y)
            + bfhi(v4.y) + bfhi(v5.y) + bfhi(v6.y) + bfhi(v7.y);
    }
    if (i < end) {   // predicated tail octet
        unsigned nm1 = (unsigned)(N - 1);
        int4 sa = *(const int4*)(adj + i);
        int4 sb = *(const int4*)(adj + i + 4);
        int s0 = sa.x;
        int s1 = (int)min((unsigned)sa.y, nm1), s2 = (int)min((unsigned)sa.z, nm1);
        int s3 = (int)min((unsigned)sa.w, nm1), s4 = (int)min((unsigned)sb.x, nm1);
        int s5 = (int)min((unsigned)sb.y, nm1), s6 = (int)min((unsigned)sb.z, nm1);
        int s7 = (int)min((unsigned)sb.w, nm1);
        uint2 v0 = gv2[(size_t)s0 * 8 + lane], v1 = gv2[(size_t)s1 * 8 + lane];
        uint2 v2 = gv2[(size_t)s2 * 8 + lane], v3 = gv2[(size_t)s3 * 8 + lane];
        uint2 v4 = gv2[(size_t)s4 * 8 + lane], v5 = gv2[(size_t)s5 * 8 + lane];
        uint2 v6 = gv2[(size_t)s6 * 8 + lane], v7 = gv2[(size_t)s7 * 8 + lane];
        if (i + 1 >= end) { v1.x = 0u; v1.y = 0u; }
        if (i + 2 >= end) { v2.x = 0u; v2.y = 0u; }
        if (i + 3 >= end) { v3.x = 0u; v3.y = 0u; }
        if (i + 4 >= end) { v4.x = 0u; v4.y = 0u; }
        if (i + 5 >= end) { v5.x = 0u; v5.y = 0u; }
        if (i + 6 >= end) { v6.x = 0u; v6.y = 0u; }
        if (i + 7 >= end) { v7.x = 0u; v7.y = 0u; }
        a0 += bflo(v0.x) + bflo(v1.x) + bflo(v2.x) + bflo(v3.x)
            + bflo(v4.x) + bflo(v5.x) + bflo(v6.x) + bflo(v7.x);
        a1 += bfhi(v0.x) + bfhi(v1.x) + bfhi(v2.x) + bfhi(v3.x)
            + bfhi(v4.x) + bfhi(v5.x) + bfhi(v6.x) + bfhi(v7.x);
        a2 += bflo(v0.y) + bflo(v1.y) + bflo(v2.y) + bflo(v3.y)
            + bflo(v4.y) + bflo(v5.y) + bflo(v6.y) + bflo(v7.y);
        a3 += bfhi(v0.y) + bfhi(v1.y) + bfhi(v2.y) + bfhi(v3.y)
            + bfhi(v4.y) + bfhi(v5.y) + bfhi(v6.y) + bfhi(v7.y);
    }

    float di = rsqrtf((float)(rc + 1));
    float4 b2v = ((const float4*)b2)[lane];
    float4 wp  = ((const float4*)Wp)[lane];
    float v = fmaxf(di * a0 + b2v.x, 0.f) * wp.x
            + fmaxf(di * a1 + b2v.y, 0.f) * wp.y
            + fmaxf(di * a2 + b2v.z, 0.f) * wp.z
            + fmaxf(di * a3 + b2v.w, 0.f) * wp.w;
#pragma unroll
    for (int off = 4; off > 0; off >>= 1) v += __shfl_down(v, off, 8);
    if (lane == 0) out[node] = fmaxf(v + hp[node], 0.f);
}

extern "C" void kernel_launch(void* const* d_in, const int* in_sizes, int n_in,
                              void* d_out, int out_size, void* d_ws, size_t ws_size,
                              hipStream_t stream) {
    const float* x  = (const float*)d_in[0];
    const int*   ei = (const int*)d_in[1];
    const float* We = (const float*)d_in[2];
    const float* be = (const float*)d_in[3];
    const float* W1 = (const float*)d_in[4];
    const float* b1 = (const float*)d_in[5];
    const float* W2 = (const float*)d_in[6];
    const float* b2 = (const float*)d_in[7];
    const float* Wp = (const float*)d_in[8];
    const float* bp = (const float*)d_in[9];
    float* out = (float*)d_out;

    const int N = in_sizes[0] / NF;
    const int E = in_sizes[1] / 2;
    const int* src = ei;
    const int* dst = ei + E;
    const int NB = (N + 255) >> BSH;                // 391
    const int nchunk = (E + BCHUNK - 1) / BCHUNK;   // 391

    size_t Np  = ((size_t)N + 127) & ~(size_t)127;
    size_t NHp = ((size_t)N * H + 127) & ~(size_t)127;
    float* ws  = (float*)d_ws;
    float* hp  = ws;                                   // Np
    __hip_bfloat16* g1 = (__hip_bfloat16*)(hp + Np);   // NHp bf16
    __hip_bfloat16* g2 = g1 + NHp;                     // NHp bf16
    __hip_bfloat16* y2 = g2 + NHp;                     // NHp bf16
    int* cursor = (int*)(y2 + NHp);                    // 512
    int* rowcnt = cursor + 512;                        // Np
    int* binned = rowcnt + Np;                         // NB*CAP
    int* adj    = binned + (size_t)NB * CAP;           // Np*CAPD

    (void)hipMemsetAsync(cursor, 0, 512 * sizeof(int), stream);
    bin_edges<<<nchunk, 512, 0, stream>>>(src, dst, cursor, binned, E, NB);
    bucket_adj<<<NB, 512, 0, stream>>>(cursor, binned, rowcnt, adj, N);

    int ngrp = (N + 7) >> 3;
    int eg = ngrp < 1536 ? ngrp : 1536;
    embed_g1<<<eg, 256, 0, stream>>>(x, We, be, W1, W2, Wp, bp, rowcnt, g1, y2, hp, N);
    agg_mid<<<(N + 31) / 32, 256, 0, stream>>>(rowcnt, adj, g1, y2, W2, b1, g2, N);
    agg_final<<<((size_t)N * 8 + 255) / 256, 256, 0, stream>>>(rowcnt, adj, g2, hp, b2, Wp, out, N);
}